// Round 12
// baseline (248.600 us; speedup 1.0000x reference)
//
#include <hip/hip_runtime.h>
#include <hip/hip_bf16.h>

// Problem constants (B=8, C=64, H=128, W=256)
#define HW_ 32768          // H*W
#define OUTHALF 16777216ULL
#define SMEM_BYTES 81920

typedef short short8  __attribute__((ext_vector_type(8)));
typedef short short4v __attribute__((ext_vector_type(4)));
typedef float f32x4   __attribute__((ext_vector_type(4)));
typedef unsigned int uint2v __attribute__((ext_vector_type(2)));
typedef unsigned int uint4v __attribute__((ext_vector_type(4)));

__device__ __forceinline__ unsigned short f2bf(float f) {
  unsigned u = __builtin_bit_cast(unsigned, f);
  u += 0x7fffu + ((u >> 16) & 1u);          // RNE; setup kernel only
  return (unsigned short)(u >> 16);
}
// native cast — compiler packs pairs into v_cvt_pk_bf16_f32 (R7-verified)
__device__ __forceinline__ short f2bfn(float f) {
  __hip_bfloat16 h = __float2bfloat16(f);
  return __builtin_bit_cast(short, h);
}
__device__ __forceinline__ unsigned pkw(float lo, float hi) {
  unsigned short a = (unsigned short)f2bfn(lo), b = (unsigned short)f2bfn(hi);
  return ((unsigned)b << 16) | (unsigned)a;
}
__device__ __forceinline__ char* swz(char* base, int row, int colByte) {
  // 128-byte rows; XOR bits 4-6 — proven for b128 reads (R1..R10)
  return base + row * 128 + (colByte ^ ((row & 7) << 4));
}
__device__ __forceinline__ char* swzV(char* base, int row, int colByte) {
  // 128-byte rows; XOR bits 5-6 only — disjoint from the K16 b64 col bits
  // (R11-verified correct)
  return base + row * 128 + (colByte ^ ((row & 3) << 5));
}
__device__ __forceinline__ f32x4 zero4() { f32x4 z = {0.f, 0.f, 0.f, 0.f}; return z; }

// In-register g-group transpose (R6-R11 verified). C-layout -> K32 A/B-fragment.
__device__ __forceinline__ void xpose(const f32x4 (&p)[4], int g,
                                      short8& f0, short8& f1) {
  unsigned W00 = pkw(p[0][0], p[0][1]), W01 = pkw(p[0][2], p[0][3]);
  unsigned W10 = pkw(p[1][0], p[1][1]), W11 = pkw(p[1][2], p[1][3]);
  unsigned W20 = pkw(p[2][0], p[2][1]), W21 = pkw(p[2][2], p[2][3]);
  unsigned W30 = pkw(p[3][0], p[3][1]), W31 = pkw(p[3][2], p[3][3]);
  const bool h2 = (g & 2) != 0;
  unsigned SA0 = h2 ? W10 : W00, SA1 = h2 ? W11 : W01;
  unsigned SA2 = h2 ? W30 : W20, SA3 = h2 ? W31 : W21;
  unsigned SB0 = h2 ? W00 : W10, SB1 = h2 ? W01 : W11;
  unsigned SB2 = h2 ? W20 : W30, SB3 = h2 ? W21 : W31;
  unsigned ra0 = __shfl_xor((int)SA0, 16), ra1 = __shfl_xor((int)SA1, 16);
  unsigned ra2 = __shfl_xor((int)SA2, 16), ra3 = __shfl_xor((int)SA3, 16);
  unsigned rb0 = __shfl_xor((int)SB0, 32), rb1 = __shfl_xor((int)SB1, 32);
  unsigned rb2 = __shfl_xor((int)SB2, 32), rb3 = __shfl_xor((int)SB3, 32);
  unsigned rc0 = __shfl_xor((int)SB0, 48), rc1 = __shfl_xor((int)SB1, 48);
  unsigned rc2 = __shfl_xor((int)SB2, 48), rc3 = __shfl_xor((int)SB3, 48);
  unsigned a0 = g==0 ? SA0 : g==1 ? rc0 : g==2 ? rb0 : ra0;
  unsigned a1 = g==0 ? SA1 : g==1 ? rc1 : g==2 ? rb1 : ra1;
  unsigned a2 = g==0 ? SA2 : g==1 ? rc2 : g==2 ? rb2 : ra2;
  unsigned a3 = g==0 ? SA3 : g==1 ? rc3 : g==2 ? rb3 : ra3;
  unsigned b0 = g==3 ? SA0 : g==2 ? rc0 : g==1 ? rb0 : ra0;
  unsigned b1 = g==3 ? SA1 : g==2 ? rc1 : g==1 ? rb1 : ra1;
  unsigned b2 = g==3 ? SA2 : g==2 ? rc2 : g==1 ? rb2 : ra2;
  unsigned b3 = g==3 ? SA3 : g==2 ? rc3 : g==1 ? rb3 : ra3;
  uint4v u0 = {a0, a1, b0, b1};
  uint4v u1 = {a2, a3, b2, b3};
  f0 = __builtin_bit_cast(short8, u0);
  f1 = __builtin_bit_cast(short8, u1);
}

// ---------------- setup: Mbt[y][x] = sum_o Wq'[o][x] Wk'[o][y] (bf16), u[y]
__global__ void pam_setup(const float* __restrict__ Wq, const float* __restrict__ bq,
                          const float* __restrict__ gq, const float* __restrict__ betaq,
                          const float* __restrict__ mq, const float* __restrict__ vq,
                          const float* __restrict__ Wk, const float* __restrict__ gk,
                          const float* __restrict__ vk,
                          short* __restrict__ Mbt, float* __restrict__ u) {
  int blk = blockIdx.x, tid = threadIdx.x;
  if (blk < 16) {
    int entry = blk * 256 + tid;
    int y = entry >> 6, x = entry & 63;
    float acc = 0.f;
    for (int o = 0; o < 64; ++o) {
      float sq = gq[o] * rsqrtf(vq[o] + 1e-5f);
      float sk = gk[o] * rsqrtf(vk[o] + 1e-5f);
      acc += Wq[o * 64 + x] * sq * Wk[o * 64 + y] * sk;
    }
    Mbt[y * 64 + x] = (short)f2bf(acc);
  } else if (tid < 64) {
    int y = tid;
    float acc = 0.f;
    for (int o = 0; o < 64; ++o) {
      float sq = gq[o] * rsqrtf(vq[o] + 1e-5f);
      float sk = gk[o] * rsqrtf(vk[o] + 1e-5f);
      float bqq = bq[o] * sq + betaq[o] - mq[o] * sq;
      acc += bqq * Wk[o * 64 + y] * sk;
    }
    u[y] = acc;
  }
}

// ---------------- main: one block per (b,h,dir); 512 thr (8 waves x 32 q);
// LDS 80KB -> 2 blocks/CU; NO aggressive VGPR cap (the R6/R11 trap).
__global__ __launch_bounds__(512, 4) void pam_main(
    const float* __restrict__ fl, const float* __restrict__ fr,
    const short* __restrict__ Mbt, const float* __restrict__ uvec,
    float* __restrict__ out) {
  extern __shared__ __align__(16) char sm[];
  char* XLt = sm;                     // [256 pos][64 c] bf16 swizzled (128B rows)
  char* XRt = sm + 32768;
  char* Xn  = sm + 65536;             // [2 buf][64 c][64 v] bf16, swzV rows

  const int tid  = threadIdx.x;
  const int lane = tid & 63;
  const int wave = tid >> 6;          // 0..7
  const int l15  = lane & 15;
  const int g    = lane >> 4;
  // T1 XCD swizzle (grid 2048 = 8 XCD x 256): paired dir-blocks of one bh
  // land on the SAME XCD -> shared slab reads L2-hit.
  const int wg = ((blockIdx.x & 7) << 8) | (blockIdx.x >> 3);
  const int bh = wg >> 1;
  const int at = wg & 1;              // direction of this block
  const int bb = bh >> 7;
  const int hh = bh & 127;
  const int rowOff = hh * 256;
  const int base_b = bb * 64;
  const int w0   = wave * 32;         // this wave's 32 query rows

  // ---- V staging role: thread stages 8 v of one channel ----
  const int vc = tid >> 3;            // channel 0..63
  const int v8 = (tid & 7) * 8;       // 8 positions
  const float* srcv = at ? fl : fr;   // key/value side
  const float* vbase = srcv + (size_t)(base_b + vc) * HW_ + rowOff + v8;

  // V tile 0 loads issued before slab staging (T14 issue-early)
  f32x4 A0 = *(const f32x4*)vbase;
  f32x4 A1 = *(const f32x4*)(vbase + 4);

  // ---- stage XLt + XRt (f32 global -> bf16 LDS, [pos][chan]) ----
  #pragma unroll
  for (int it = 0; it < 16; ++it) {
    int unit = it * 512 + tid;        // 0..8191
    int tensor = unit >> 12;
    int rem = unit & 4095;
    int cq = rem >> 8;                // channel quad 0..15
    int p  = rem & 255;               // position
    const float* s = (tensor ? fr : fl) + (size_t)(base_b + cq * 4) * HW_ + rowOff + p;
    float v0 = s[0], v1 = s[HW_], v2 = s[2 * HW_], v3 = s[3 * HW_];
    short4v pk;
    pk[0] = f2bfn(v0); pk[1] = f2bfn(v1);
    pk[2] = f2bfn(v2); pk[3] = f2bfn(v3);
    *(short4v*)swz(tensor ? XRt : XLt, p, cq * 8) = pk;
  }
  // ---- V tile 0 -> buf 0; prefetch tile 1 ----
  {
    short8 pk;
    pk[0] = f2bfn(A0[0]); pk[1] = f2bfn(A0[1]);
    pk[2] = f2bfn(A0[2]); pk[3] = f2bfn(A0[3]);
    pk[4] = f2bfn(A1[0]); pk[5] = f2bfn(A1[1]);
    pk[6] = f2bfn(A1[2]); pk[7] = f2bfn(A1[3]);
    *(short8*)swzV(Xn, vc, v8 * 2) = pk;
  }
  A0 = *(const f32x4*)(vbase + 64);
  A1 = *(const f32x4*)(vbase + 68);
  __syncthreads();                    // slabs + V buf0 visible

  char* Xq  = at ? XRt : XLt;         // query side
  char* Xkv = at ? XLt : XRt;         // key/value side (S-GEMM A operand)

  // ---- Q^ = M^T Xq + u for this wave's 32 rows; one-time xpose ----
  short8 bq_[2][2];                   // [nj][kk]
  #pragma unroll
  for (int nj = 0; nj < 2; ++nj) {
    short8 xb0 = *(const short8*)swz(Xq, w0 + nj * 16 + l15, (8 * g) * 2);
    short8 xb1 = *(const short8*)swz(Xq, w0 + nj * 16 + l15, (32 + 8 * g) * 2);
    f32x4 qa[4];
    #pragma unroll
    for (int mi = 0; mi < 4; ++mi) {
      qa[mi] = zero4();
      short8 am0 = *(const short8*)(Mbt + (mi * 16 + l15) * 64 + 8 * g);
      short8 am1 = *(const short8*)(Mbt + (mi * 16 + l15) * 64 + 32 + 8 * g);
      qa[mi] = __builtin_amdgcn_mfma_f32_16x16x32_bf16(am0, xb0, qa[mi], 0, 0, 0);
      qa[mi] = __builtin_amdgcn_mfma_f32_16x16x32_bf16(am1, xb1, qa[mi], 0, 0, 0);
      f32x4 uv = *(const f32x4*)(uvec + mi * 16 + 4 * g);
      #pragma unroll
      for (int r = 0; r < 4; ++r) qa[mi][r] += uv[r];
    }
    xpose(qa, g, bq_[nj][0], bq_[nj][1]);
  }

  // ---- accumulators (32 q/wave) ----
  f32x4 acc_o[2][4];                  // [nj][c-group]
  #pragma unroll
  for (int i = 0; i < 2; ++i)
    #pragma unroll
    for (int j = 0; j < 4; ++j) acc_o[i][j] = zero4();
  float dacc0 = 0.f, dacc1 = 0.f;

  #pragma unroll
  for (int vt = 0; vt < 4; ++vt) {
    // ---- stage V(vt+1) into the other buffer; issue loads for vt+2 ----
    if (vt < 3) {
      short8 pk;
      pk[0] = f2bfn(A0[0]); pk[1] = f2bfn(A0[1]);
      pk[2] = f2bfn(A0[2]); pk[3] = f2bfn(A0[3]);
      pk[4] = f2bfn(A1[0]); pk[5] = f2bfn(A1[1]);
      pk[6] = f2bfn(A1[2]); pk[7] = f2bfn(A1[3]);
      *(short8*)swzV(Xn + ((vt + 1) & 1) * 8192, vc, v8 * 2) = pk;
      if (vt < 2) {
        A0 = *(const f32x4*)(vbase + (vt + 2) * 64);
        A1 = *(const f32x4*)(vbase + (vt + 2) * 64 + 4);
      }
    }
    char* XnB = Xn + (vt & 1) * 8192;

    // ---- fused per-mi: S-GEMM (K32) -> exp -> pack -> PV (K16) ----
    #pragma unroll
    for (int mi = 0; mi < 4; ++mi) {
      short8 af0 = *(const short8*)swz(Xkv, vt * 64 + mi * 16 + l15, (8 * g) * 2);
      short8 af1 = *(const short8*)swz(Xkv, vt * 64 + mi * 16 + l15, (32 + 8 * g) * 2);
      short4v bv[4];
      #pragma unroll
      for (int nj2 = 0; nj2 < 4; ++nj2)
        bv[nj2] = *(const short4v*)swzV(XnB, nj2 * 16 + l15, (mi * 16 + 4 * g) * 2);
      #pragma unroll
      for (int nj = 0; nj < 2; ++nj) {
        f32x4 ps = zero4();
        ps = __builtin_amdgcn_mfma_f32_16x16x32_bf16(af0, bq_[nj][0], ps, 0, 0, 0);
        ps = __builtin_amdgcn_mfma_f32_16x16x32_bf16(af1, bq_[nj][1], ps, 0, 0, 0);
        #pragma unroll
        for (int r = 0; r < 4; ++r)
          ps[r] = __expf(ps[r] * 0.015625f);
        if (nj == 0) dacc0 += ps[0] + ps[1] + ps[2] + ps[3];
        else         dacc1 += ps[0] + ps[1] + ps[2] + ps[3];
        uint2v pw;
        pw[0] = pkw(ps[0], ps[1]);
        pw[1] = pkw(ps[2], ps[3]);
        short4v pa = __builtin_bit_cast(short4v, pw);
        #pragma unroll
        for (int nj2 = 0; nj2 < 4; ++nj2)
          acc_o[nj][nj2] = __builtin_amdgcn_mfma_f32_16x16x16bf16_1k(
              pa, bv[nj2], acc_o[nj][nj2], 0, 0, 0);
      }
    }
    if (vt < 3) __syncthreads();      // V(vt+1) visible / buf(vt) free next round
  } // vt

  // ---- D redistribute via shuffles (no LDS, R11-verified) + epilogue ----
  dacc0 += __shfl_xor(dacc0, 16); dacc0 += __shfl_xor(dacc0, 32);
  dacc1 += __shfl_xor(dacc1, 16); dacc1 += __shfl_xor(dacc1, 32);
  float dinv0 = __builtin_amdgcn_rcpf(dacc0);  // lane(l15,*): 1/D[w0+l15]
  float dinv1 = __builtin_amdgcn_rcpf(dacc1);  // lane(l15,*): 1/D[w0+16+l15]
  float* outp = out + (at ? OUTHALF : 0) + (size_t)base_b * HW_ + rowOff;
  #pragma unroll
  for (int nj = 0; nj < 2; ++nj) {
    f32x4 rd;
    #pragma unroll
    for (int r = 0; r < 4; ++r)
      rd[r] = __shfl(nj ? dinv1 : dinv0, 4 * g + r);
    #pragma unroll
    for (int nj2 = 0; nj2 < 4; ++nj2) {
      int c = nj2 * 16 + l15;
      f32x4 v;
      v[0] = acc_o[nj][nj2][0] * rd[0];
      v[1] = acc_o[nj][nj2][1] * rd[1];
      v[2] = acc_o[nj][nj2][2] * rd[2];
      v[3] = acc_o[nj][nj2][3] * rd[3];
      *(f32x4*)(outp + (size_t)c * HW_ + w0 + nj * 16 + 4 * g) = v;
    }
  }
}

extern "C" void kernel_launch(void* const* d_in, const int* in_sizes, int n_in,
                              void* d_out, int out_size, void* d_ws, size_t ws_size,
                              hipStream_t stream) {
  (void)in_sizes; (void)n_in; (void)out_size; (void)ws_size;
  const float* fl    = (const float*)d_in[0];
  const float* fr    = (const float*)d_in[1];
  const float* Wq    = (const float*)d_in[2];
  const float* bq    = (const float*)d_in[3];
  const float* gq    = (const float*)d_in[4];
  const float* betaq = (const float*)d_in[5];
  const float* mq    = (const float*)d_in[6];
  const float* vq    = (const float*)d_in[7];
  const float* Wk    = (const float*)d_in[8];
  const float* gk    = (const float*)d_in[10];
  const float* vk    = (const float*)d_in[13];
  short* Mbt = (short*)d_ws;
  float* u   = (float*)((char*)d_ws + 8192);
  float* out = (float*)d_out;

  hipFuncSetAttribute((const void*)pam_main,
                      hipFuncAttributeMaxDynamicSharedMemorySize, SMEM_BYTES);
  pam_setup<<<17, 256, 0, stream>>>(Wq, bq, gq, betaq, mq, vq, Wk, gk, vk, Mbt, u);
  pam_main<<<2048, 512, SMEM_BYTES, stream>>>(fl, fr, Mbt, u, out);
}

// Round 13
// 139.944 us; speedup vs baseline: 1.7764x; 1.7764x over previous
//
#include <hip/hip_runtime.h>
#include <hip/hip_bf16.h>

// Problem constants (B=8, C=64, H=128, W=256)
#define HW_ 32768          // H*W
#define OUTHALF 16777216ULL
#define SMEM_BYTES 131072

typedef short short8  __attribute__((ext_vector_type(8)));
typedef short short4v __attribute__((ext_vector_type(4)));
typedef float f32x4   __attribute__((ext_vector_type(4)));
typedef unsigned int uint2v __attribute__((ext_vector_type(2)));
typedef unsigned int uint4v __attribute__((ext_vector_type(4)));

__device__ __forceinline__ unsigned short f2bf(float f) {
  unsigned u = __builtin_bit_cast(unsigned, f);
  u += 0x7fffu + ((u >> 16) & 1u);          // RNE; setup kernel only
  return (unsigned short)(u >> 16);
}
// native cast — compiler packs pairs into v_cvt_pk_bf16_f32 (R7-verified)
__device__ __forceinline__ short f2bfn(float f) {
  __hip_bfloat16 h = __float2bfloat16(f);
  return __builtin_bit_cast(short, h);
}
__device__ __forceinline__ unsigned pkw(float lo, float hi) {
  unsigned short a = (unsigned short)f2bfn(lo), b = (unsigned short)f2bfn(hi);
  return ((unsigned)b << 16) | (unsigned)a;
}
__device__ __forceinline__ char* swz(char* base, int row, int colByte) {
  // 128-byte rows; XOR bits 4-6 — proven for b128 reads (R1..R10)
  return base + row * 128 + (colByte ^ ((row & 7) << 4));
}
__device__ __forceinline__ char* swzV(char* base, int row, int colByte) {
  // 128-byte rows; XOR bits 5-6 only — disjoint from the K16 b64 col bits
  // (bits 3-4), halves bv-read conflicts vs swz (R11/R12-verified correct)
  return base + row * 128 + (colByte ^ ((row & 3) << 5));
}
__device__ __forceinline__ f32x4 zero4() { f32x4 z = {0.f, 0.f, 0.f, 0.f}; return z; }

// In-register g-group transpose (R6-R12 verified). C-layout -> K32 A/B-fragment.
// Used once for the Q~ fragments.
__device__ __forceinline__ void xpose(const f32x4 (&p)[4], int g,
                                      short8& f0, short8& f1) {
  unsigned W00 = pkw(p[0][0], p[0][1]), W01 = pkw(p[0][2], p[0][3]);
  unsigned W10 = pkw(p[1][0], p[1][1]), W11 = pkw(p[1][2], p[1][3]);
  unsigned W20 = pkw(p[2][0], p[2][1]), W21 = pkw(p[2][2], p[2][3]);
  unsigned W30 = pkw(p[3][0], p[3][1]), W31 = pkw(p[3][2], p[3][3]);
  const bool h2 = (g & 2) != 0;
  unsigned SA0 = h2 ? W10 : W00, SA1 = h2 ? W11 : W01;
  unsigned SA2 = h2 ? W30 : W20, SA3 = h2 ? W31 : W21;
  unsigned SB0 = h2 ? W00 : W10, SB1 = h2 ? W01 : W11;
  unsigned SB2 = h2 ? W20 : W30, SB3 = h2 ? W21 : W31;
  unsigned ra0 = __shfl_xor((int)SA0, 16), ra1 = __shfl_xor((int)SA1, 16);
  unsigned ra2 = __shfl_xor((int)SA2, 16), ra3 = __shfl_xor((int)SA3, 16);
  unsigned rb0 = __shfl_xor((int)SB0, 32), rb1 = __shfl_xor((int)SB1, 32);
  unsigned rb2 = __shfl_xor((int)SB2, 32), rb3 = __shfl_xor((int)SB3, 32);
  unsigned rc0 = __shfl_xor((int)SB0, 48), rc1 = __shfl_xor((int)SB1, 48);
  unsigned rc2 = __shfl_xor((int)SB2, 48), rc3 = __shfl_xor((int)SB3, 48);
  unsigned a0 = g==0 ? SA0 : g==1 ? rc0 : g==2 ? rb0 : ra0;
  unsigned a1 = g==0 ? SA1 : g==1 ? rc1 : g==2 ? rb1 : ra1;
  unsigned a2 = g==0 ? SA2 : g==1 ? rc2 : g==2 ? rb2 : ra2;
  unsigned a3 = g==0 ? SA3 : g==1 ? rc3 : g==2 ? rb3 : ra3;
  unsigned b0 = g==3 ? SA0 : g==2 ? rc0 : g==1 ? rb0 : ra0;
  unsigned b1 = g==3 ? SA1 : g==2 ? rc1 : g==1 ? rb1 : ra1;
  unsigned b2 = g==3 ? SA2 : g==2 ? rc2 : g==1 ? rb2 : ra2;
  unsigned b3 = g==3 ? SA3 : g==2 ? rc3 : g==1 ? rb3 : ra3;
  uint4v u0 = {a0, a1, b0, b1};
  uint4v u1 = {a2, a3, b2, b3};
  f0 = __builtin_bit_cast(short8, u0);
  f1 = __builtin_bit_cast(short8, u1);
}

// ---------------- setup: Mbt[y][x] = sum_o Wq'[o][x] Wk'[o][y] (bf16), u[y]
__global__ void pam_setup(const float* __restrict__ Wq, const float* __restrict__ bq,
                          const float* __restrict__ gq, const float* __restrict__ betaq,
                          const float* __restrict__ mq, const float* __restrict__ vq,
                          const float* __restrict__ Wk, const float* __restrict__ gk,
                          const float* __restrict__ vk,
                          short* __restrict__ Mbt, float* __restrict__ u) {
  int blk = blockIdx.x, tid = threadIdx.x;
  if (blk < 16) {
    int entry = blk * 256 + tid;
    int y = entry >> 6, x = entry & 63;
    float acc = 0.f;
    for (int o = 0; o < 64; ++o) {
      float sq = gq[o] * rsqrtf(vq[o] + 1e-5f);
      float sk = gk[o] * rsqrtf(vk[o] + 1e-5f);
      acc += Wq[o * 64 + x] * sq * Wk[o * 64 + y] * sk;
    }
    Mbt[y * 64 + x] = (short)f2bf(acc);
  } else if (tid < 64) {
    int y = tid;
    float acc = 0.f;
    for (int o = 0; o < 64; ++o) {
      float sq = gq[o] * rsqrtf(vq[o] + 1e-5f);
      float sk = gk[o] * rsqrtf(vk[o] + 1e-5f);
      float bqq = bq[o] * sq + betaq[o] - mq[o] * sq;
      acc += bqq * Wk[o * 64 + y] * sk;
    }
    u[y] = acc;
  }
}

// ---------------- main: one block per (b,h); waves 0-7: at=0, waves 8-15: at=1.
// Single barrier; K16 PV consumes P in C-layout (R10 structure, swzV Xn).
__global__ __launch_bounds__(1024, 4) void pam_main(
    const float* __restrict__ fl, const float* __restrict__ fr,
    const short* __restrict__ Mbt, const float* __restrict__ uvec,
    float* __restrict__ out) {
  extern __shared__ __align__(16) char sm[];
  char* XLt = sm;                     // [256 pos][64 c] bf16 swizzled (128B rows)
  char* XRt = sm + 32768;
  char* Xn  = sm + 65536;             // [2 dir][4 vt][64 c][64 v] bf16, swzV rows

  const int tid  = threadIdx.x;
  const int lane = tid & 63;
  const int wave = tid >> 6;          // 0..15
  const int l15  = lane & 15;
  const int g    = lane >> 4;
  const int bb   = blockIdx.x >> 7;
  const int hh   = blockIdx.x & 127;
  const int rowOff = hh * 256;
  const int base_b = bb * 64;
  const int at   = wave >> 3;         // direction of this wave
  const int w0   = (wave & 7) * 32;   // this wave's 32 query rows

  // ---- stage XLt + XRt (f32 global -> bf16 LDS, [pos][chan]) ----
  #pragma unroll
  for (int it = 0; it < 8; ++it) {
    int unit = it * 1024 + tid;       // 0..8191
    int tensor = unit >> 12;
    int rem = unit & 4095;
    int cq = rem >> 8;                // channel quad 0..15
    int p  = rem & 255;               // position
    const float* s = (tensor ? fr : fl) + (size_t)(base_b + cq * 4) * HW_ + rowOff + p;
    float v0 = s[0], v1 = s[HW_], v2 = s[2 * HW_], v3 = s[3 * HW_];
    short4v pk;
    pk[0] = f2bfn(v0); pk[1] = f2bfn(v1);
    pk[2] = f2bfn(v2); pk[3] = f2bfn(v3);
    *(short4v*)swz(tensor ? XRt : XLt, p, cq * 8) = pk;
  }
  // ---- stage V for both directions: Xn[dir][vt][c][v], swzV 128B rows ----
  {
    const int dirT = tid >> 9;        // threads 0-511: dir0 (fr), 512-1023: dir1 (fl)
    const int vcc  = (tid >> 3) & 63; // channel
    const int vv8  = (tid & 7) * 8;   // 8 positions
    const float* srcv = dirT ? fl : fr;
    const float* vbase = srcv + (size_t)(base_b + vcc) * HW_ + rowOff + vv8;
    char* XnW = Xn + dirT * 32768;
    #pragma unroll
    for (int vt = 0; vt < 4; ++vt) {
      f32x4 A0 = *(const f32x4*)(vbase + vt * 64);
      f32x4 A1 = *(const f32x4*)(vbase + vt * 64 + 4);
      short8 pk;
      pk[0] = f2bfn(A0[0]); pk[1] = f2bfn(A0[1]);
      pk[2] = f2bfn(A0[2]); pk[3] = f2bfn(A0[3]);
      pk[4] = f2bfn(A1[0]); pk[5] = f2bfn(A1[1]);
      pk[6] = f2bfn(A1[2]); pk[7] = f2bfn(A1[3]);
      *(short8*)swzV(XnW + vt * 8192, vcc, vv8 * 2) = pk;
    }
  }
  __syncthreads();                    // the ONLY barrier

  char* Xq  = at ? XRt : XLt;         // query side
  char* Xkv = at ? XLt : XRt;         // key/value side (S-GEMM A operand)
  char* XnC = Xn + at * 32768;        // this direction's V

  // ---- Q^ = M^T Xq + u (u-fold; no t-phase); one-time xpose ----
  short8 bq_[2][2];                   // [nj][kk]
  #pragma unroll
  for (int nj = 0; nj < 2; ++nj) {
    short8 xb0 = *(const short8*)swz(Xq, w0 + nj * 16 + l15, (8 * g) * 2);
    short8 xb1 = *(const short8*)swz(Xq, w0 + nj * 16 + l15, (32 + 8 * g) * 2);
    f32x4 qa[4];
    #pragma unroll
    for (int mi = 0; mi < 4; ++mi) {
      qa[mi] = zero4();
      short8 am0 = *(const short8*)(Mbt + (mi * 16 + l15) * 64 + 8 * g);
      short8 am1 = *(const short8*)(Mbt + (mi * 16 + l15) * 64 + 32 + 8 * g);
      qa[mi] = __builtin_amdgcn_mfma_f32_16x16x32_bf16(am0, xb0, qa[mi], 0, 0, 0);
      qa[mi] = __builtin_amdgcn_mfma_f32_16x16x32_bf16(am1, xb1, qa[mi], 0, 0, 0);
      f32x4 uv = *(const f32x4*)(uvec + mi * 16 + 4 * g);
      #pragma unroll
      for (int r = 0; r < 4; ++r) qa[mi][r] += uv[r];
    }
    xpose(qa, g, bq_[nj][0], bq_[nj][1]);
  }

  // ---- accumulators ----
  f32x4 acc_o[2][4];                  // [nj][c-group]
  #pragma unroll
  for (int i = 0; i < 2; ++i)
    #pragma unroll
    for (int j = 0; j < 4; ++j) acc_o[i][j] = zero4();
  float dacc0 = 0.f, dacc1 = 0.f;

  #pragma unroll
  for (int vt = 0; vt < 4; ++vt) {
    // ---- S-GEMM (K32): ps[nj][mi] = S_T[v=16mi+4g+r][w=l15] ----
    f32x4 ps[2][4];
    #pragma unroll
    for (int mi = 0; mi < 4; ++mi) {
      short8 af0 = *(const short8*)swz(Xkv, vt * 64 + mi * 16 + l15, (8 * g) * 2);
      short8 af1 = *(const short8*)swz(Xkv, vt * 64 + mi * 16 + l15, (32 + 8 * g) * 2);
      #pragma unroll
      for (int nj = 0; nj < 2; ++nj) {
        ps[nj][mi] = zero4();
        ps[nj][mi] = __builtin_amdgcn_mfma_f32_16x16x32_bf16(af0, bq_[nj][0], ps[nj][mi], 0, 0, 0);
        ps[nj][mi] = __builtin_amdgcn_mfma_f32_16x16x32_bf16(af1, bq_[nj][1], ps[nj][mi], 0, 0, 0);
      }
    }
    // ---- exp (in place) + D accumulation ----
    #pragma unroll
    for (int nj = 0; nj < 2; ++nj) {
      float dl = 0.f;
      #pragma unroll
      for (int mi = 0; mi < 4; ++mi) {
        #pragma unroll
        for (int r = 0; r < 4; ++r)
          ps[nj][mi][r] = __expf(ps[nj][mi][r] * 0.015625f);
        dl += ps[nj][mi][0] + ps[nj][mi][1] + ps[nj][mi][2] + ps[nj][mi][3];
      }
      if (nj == 0) dacc0 += dl; else dacc1 += dl;
    }
    // ---- PV-GEMM (K16): P in C-layout is the A-fragment directly ----
    char* XnT = XnC + vt * 8192;
    #pragma unroll
    for (int mi = 0; mi < 4; ++mi) {
      short4v bv[4];
      #pragma unroll
      for (int nj2 = 0; nj2 < 4; ++nj2)
        bv[nj2] = *(const short4v*)swzV(XnT, nj2 * 16 + l15, (mi * 16 + 4 * g) * 2);
      #pragma unroll
      for (int nj = 0; nj < 2; ++nj) {
        uint2v pw;
        pw[0] = pkw(ps[nj][mi][0], ps[nj][mi][1]);
        pw[1] = pkw(ps[nj][mi][2], ps[nj][mi][3]);
        short4v pa = __builtin_bit_cast(short4v, pw);
        #pragma unroll
        for (int nj2 = 0; nj2 < 4; ++nj2)
          acc_o[nj][nj2] = __builtin_amdgcn_mfma_f32_16x16x16bf16_1k(
              pa, bv[nj2], acc_o[nj][nj2], 0, 0, 0);
      }
    }
  } // vt

  // ---- D redistribute via shuffles (R11/R12-verified) + epilogue ----
  dacc0 += __shfl_xor(dacc0, 16); dacc0 += __shfl_xor(dacc0, 32);
  dacc1 += __shfl_xor(dacc1, 16); dacc1 += __shfl_xor(dacc1, 32);
  float dinv0 = __builtin_amdgcn_rcpf(dacc0);  // lane(l15,*): 1/D[w0+l15]
  float dinv1 = __builtin_amdgcn_rcpf(dacc1);  // lane(l15,*): 1/D[w0+16+l15]
  float* outp = out + (at ? OUTHALF : 0) + (size_t)base_b * HW_ + rowOff;
  #pragma unroll
  for (int nj = 0; nj < 2; ++nj) {
    f32x4 rd;
    #pragma unroll
    for (int r = 0; r < 4; ++r)
      rd[r] = __shfl(nj ? dinv1 : dinv0, 4 * g + r);
    #pragma unroll
    for (int nj2 = 0; nj2 < 4; ++nj2) {
      int c = nj2 * 16 + l15;
      f32x4 v;
      v[0] = acc_o[nj][nj2][0] * rd[0];
      v[1] = acc_o[nj][nj2][1] * rd[1];
      v[2] = acc_o[nj][nj2][2] * rd[2];
      v[3] = acc_o[nj][nj2][3] * rd[3];
      *(f32x4*)(outp + (size_t)c * HW_ + w0 + nj * 16 + 4 * g) = v;
    }
  }
}

extern "C" void kernel_launch(void* const* d_in, const int* in_sizes, int n_in,
                              void* d_out, int out_size, void* d_ws, size_t ws_size,
                              hipStream_t stream) {
  (void)in_sizes; (void)n_in; (void)out_size; (void)ws_size;
  const float* fl    = (const float*)d_in[0];
  const float* fr    = (const float*)d_in[1];
  const float* Wq    = (const float*)d_in[2];
  const float* bq    = (const float*)d_in[3];
  const float* gq    = (const float*)d_in[4];
  const float* betaq = (const float*)d_in[5];
  const float* mq    = (const float*)d_in[6];
  const float* vq    = (const float*)d_in[7];
  const float* Wk    = (const float*)d_in[8];
  const float* gk    = (const float*)d_in[10];
  const float* vk    = (const float*)d_in[13];
  short* Mbt = (short*)d_ws;
  float* u   = (float*)((char*)d_ws + 8192);
  float* out = (float*)d_out;

  hipFuncSetAttribute((const void*)pam_main,
                      hipFuncAttributeMaxDynamicSharedMemorySize, SMEM_BYTES);
  pam_setup<<<17, 256, 0, stream>>>(Wq, bq, gq, betaq, mq, vq, Wk, gk, vk, Mbt, u);
  pam_main<<<1024, 1024, SMEM_BYTES, stream>>>(fl, fr, Mbt, u, out);
}

// Round 14
// 115.667 us; speedup vs baseline: 2.1493x; 1.2099x over previous
//
#include <hip/hip_runtime.h>
#include <hip/hip_bf16.h>

// Problem constants (B=8, C=64, H=128, W=256)
#define HW_ 32768          // H*W
#define OUTHALF 16777216ULL
#define SMEM_BYTES 141312

typedef short short8  __attribute__((ext_vector_type(8)));
typedef short short4v __attribute__((ext_vector_type(4)));
typedef float f32x4   __attribute__((ext_vector_type(4)));
typedef unsigned int uint2v __attribute__((ext_vector_type(2)));
typedef unsigned int uint4v __attribute__((ext_vector_type(4)));

__device__ __forceinline__ unsigned short f2bf(float f) {
  unsigned u = __builtin_bit_cast(unsigned, f);
  u += 0x7fffu + ((u >> 16) & 1u);          // RNE; setup kernel only
  return (unsigned short)(u >> 16);
}
// native cast — compiler packs pairs into v_cvt_pk_bf16_f32 (R7-verified)
__device__ __forceinline__ short f2bfn(float f) {
  __hip_bfloat16 h = __float2bfloat16(f);
  return __builtin_bit_cast(short, h);
}
__device__ __forceinline__ unsigned pkw(float lo, float hi) {
  unsigned short a = (unsigned short)f2bfn(lo), b = (unsigned short)f2bfn(hi);
  return ((unsigned)b << 16) | (unsigned)a;
}
__device__ __forceinline__ char* swz(char* base, int row, int colByte) {
  // 128-byte rows; XOR bits 4-6 — proven for b128 reads (R1..R10)
  return base + row * 128 + (colByte ^ ((row & 7) << 4));
}
__device__ __forceinline__ f32x4 zero4() { f32x4 z = {0.f, 0.f, 0.f, 0.f}; return z; }

// In-register g-group transpose (R6-R13 verified). C-layout -> K32 A/B-fragment.
// Used once for the Q~ fragments.
__device__ __forceinline__ void xpose(const f32x4 (&p)[4], int g,
                                      short8& f0, short8& f1) {
  unsigned W00 = pkw(p[0][0], p[0][1]), W01 = pkw(p[0][2], p[0][3]);
  unsigned W10 = pkw(p[1][0], p[1][1]), W11 = pkw(p[1][2], p[1][3]);
  unsigned W20 = pkw(p[2][0], p[2][1]), W21 = pkw(p[2][2], p[2][3]);
  unsigned W30 = pkw(p[3][0], p[3][1]), W31 = pkw(p[3][2], p[3][3]);
  const bool h2 = (g & 2) != 0;
  unsigned SA0 = h2 ? W10 : W00, SA1 = h2 ? W11 : W01;
  unsigned SA2 = h2 ? W30 : W20, SA3 = h2 ? W31 : W21;
  unsigned SB0 = h2 ? W00 : W10, SB1 = h2 ? W01 : W11;
  unsigned SB2 = h2 ? W20 : W30, SB3 = h2 ? W21 : W31;
  unsigned ra0 = __shfl_xor((int)SA0, 16), ra1 = __shfl_xor((int)SA1, 16);
  unsigned ra2 = __shfl_xor((int)SA2, 16), ra3 = __shfl_xor((int)SA3, 16);
  unsigned rb0 = __shfl_xor((int)SB0, 32), rb1 = __shfl_xor((int)SB1, 32);
  unsigned rb2 = __shfl_xor((int)SB2, 32), rb3 = __shfl_xor((int)SB3, 32);
  unsigned rc0 = __shfl_xor((int)SB0, 48), rc1 = __shfl_xor((int)SB1, 48);
  unsigned rc2 = __shfl_xor((int)SB2, 48), rc3 = __shfl_xor((int)SB3, 48);
  unsigned a0 = g==0 ? SA0 : g==1 ? rc0 : g==2 ? rb0 : ra0;
  unsigned a1 = g==0 ? SA1 : g==1 ? rc1 : g==2 ? rb1 : ra1;
  unsigned a2 = g==0 ? SA2 : g==1 ? rc2 : g==2 ? rb2 : ra2;
  unsigned a3 = g==0 ? SA3 : g==1 ? rc3 : g==2 ? rb3 : ra3;
  unsigned b0 = g==3 ? SA0 : g==2 ? rc0 : g==1 ? rb0 : ra0;
  unsigned b1 = g==3 ? SA1 : g==2 ? rc1 : g==1 ? rb1 : ra1;
  unsigned b2 = g==3 ? SA2 : g==2 ? rc2 : g==1 ? rb2 : ra2;
  unsigned b3 = g==3 ? SA3 : g==2 ? rc3 : g==1 ? rb3 : ra3;
  uint4v u0 = {a0, a1, b0, b1};
  uint4v u1 = {a2, a3, b2, b3};
  f0 = __builtin_bit_cast(short8, u0);
  f1 = __builtin_bit_cast(short8, u1);
}

// ---------------- setup: Mbt[y][x] = sum_o Wq'[o][x] Wk'[o][y] (bf16), u[y]
__global__ void pam_setup(const float* __restrict__ Wq, const float* __restrict__ bq,
                          const float* __restrict__ gq, const float* __restrict__ betaq,
                          const float* __restrict__ mq, const float* __restrict__ vq,
                          const float* __restrict__ Wk, const float* __restrict__ gk,
                          const float* __restrict__ vk,
                          short* __restrict__ Mbt, float* __restrict__ u) {
  int blk = blockIdx.x, tid = threadIdx.x;
  if (blk < 16) {
    int entry = blk * 256 + tid;
    int y = entry >> 6, x = entry & 63;
    float acc = 0.f;
    for (int o = 0; o < 64; ++o) {
      float sq = gq[o] * rsqrtf(vq[o] + 1e-5f);
      float sk = gk[o] * rsqrtf(vk[o] + 1e-5f);
      acc += Wq[o * 64 + x] * sq * Wk[o * 64 + y] * sk;
    }
    Mbt[y * 64 + x] = (short)f2bf(acc);
  } else if (tid < 64) {
    int y = tid;
    float acc = 0.f;
    for (int o = 0; o < 64; ++o) {
      float sq = gq[o] * rsqrtf(vq[o] + 1e-5f);
      float sk = gk[o] * rsqrtf(vk[o] + 1e-5f);
      float bqq = bq[o] * sq + betaq[o] - mq[o] * sq;
      acc += bqq * Wk[o * 64 + y] * sk;
    }
    u[y] = acc;
  }
}

// ---------------- main: one block per (b,h); waves 0-7: at=0, waves 8-15: at=1.
// R10 structure exactly; Xn uses PADDED 144B rows (no XOR) to kill bv conflicts.
__global__ __launch_bounds__(1024, 4) void pam_main(
    const float* __restrict__ fl, const float* __restrict__ fr,
    const short* __restrict__ Mbt, const float* __restrict__ uvec,
    float* __restrict__ out) {
  extern __shared__ __align__(16) char sm[];
  char* XLt = sm;                     // [256 pos][64 c] bf16 swizzled (128B rows)
  char* XRt = sm + 32768;
  char* Xn  = sm + 65536;             // [2 dir][4 vt][64 c][144B] padded rows
  float* Db = (float*)(sm + 139264);  // [2][256] 1/D

  const int tid  = threadIdx.x;
  const int lane = tid & 63;
  const int wave = tid >> 6;          // 0..15
  const int l15  = lane & 15;
  const int g    = lane >> 4;
  const int bb   = blockIdx.x >> 7;
  const int hh   = blockIdx.x & 127;
  const int rowOff = hh * 256;
  const int base_b = bb * 64;
  const int at   = wave >> 3;         // direction of this wave
  const int w0   = (wave & 7) * 32;   // this wave's 32 query rows

  // ---- stage XLt + XRt (f32 global -> bf16 LDS, [pos][chan]) ----
  #pragma unroll
  for (int it = 0; it < 8; ++it) {
    int unit = it * 1024 + tid;       // 0..8191
    int tensor = unit >> 12;
    int rem = unit & 4095;
    int cq = rem >> 8;                // channel quad 0..15
    int p  = rem & 255;               // position
    const float* s = (tensor ? fr : fl) + (size_t)(base_b + cq * 4) * HW_ + rowOff + p;
    float v0 = s[0], v1 = s[HW_], v2 = s[2 * HW_], v3 = s[3 * HW_];
    short4v pk;
    pk[0] = f2bfn(v0); pk[1] = f2bfn(v1);
    pk[2] = f2bfn(v2); pk[3] = f2bfn(v3);
    *(short4v*)swz(tensor ? XRt : XLt, p, cq * 8) = pk;
  }
  // ---- stage V for both directions: Xn[dir][vt][c][144B] padded rows ----
  {
    const int dirT = tid >> 9;        // threads 0-511: dir0 (fr), 512-1023: dir1 (fl)
    const int vcc  = (tid >> 3) & 63; // channel
    const int vv8  = (tid & 7) * 8;   // 8 positions
    const float* srcv = dirT ? fl : fr;
    const float* vbase = srcv + (size_t)(base_b + vcc) * HW_ + rowOff + vv8;
    char* XnW = Xn + dirT * 36864 + vcc * 144 + vv8 * 2;
    #pragma unroll
    for (int vt = 0; vt < 4; ++vt) {
      f32x4 A0 = *(const f32x4*)(vbase + vt * 64);
      f32x4 A1 = *(const f32x4*)(vbase + vt * 64 + 4);
      short8 pk;
      pk[0] = f2bfn(A0[0]); pk[1] = f2bfn(A0[1]);
      pk[2] = f2bfn(A0[2]); pk[3] = f2bfn(A0[3]);
      pk[4] = f2bfn(A1[0]); pk[5] = f2bfn(A1[1]);
      pk[6] = f2bfn(A1[2]); pk[7] = f2bfn(A1[3]);
      *(short8*)(XnW + vt * 9216) = pk;
    }
  }
  __syncthreads();                    // the ONLY barrier

  char* Xq  = at ? XRt : XLt;         // query side
  char* Xkv = at ? XLt : XRt;         // key/value side (S-GEMM A operand)
  char* XnC = Xn + at * 36864;        // this direction's V

  // ---- Q^ = M^T Xq + u (u-fold; no t-phase); one-time xpose ----
  short8 bq_[2][2];                   // [nj][kk]
  #pragma unroll
  for (int nj = 0; nj < 2; ++nj) {
    short8 xb0 = *(const short8*)swz(Xq, w0 + nj * 16 + l15, (8 * g) * 2);
    short8 xb1 = *(const short8*)swz(Xq, w0 + nj * 16 + l15, (32 + 8 * g) * 2);
    f32x4 qa[4];
    #pragma unroll
    for (int mi = 0; mi < 4; ++mi) {
      qa[mi] = zero4();
      short8 am0 = *(const short8*)(Mbt + (mi * 16 + l15) * 64 + 8 * g);
      short8 am1 = *(const short8*)(Mbt + (mi * 16 + l15) * 64 + 32 + 8 * g);
      qa[mi] = __builtin_amdgcn_mfma_f32_16x16x32_bf16(am0, xb0, qa[mi], 0, 0, 0);
      qa[mi] = __builtin_amdgcn_mfma_f32_16x16x32_bf16(am1, xb1, qa[mi], 0, 0, 0);
      f32x4 uv = *(const f32x4*)(uvec + mi * 16 + 4 * g);
      #pragma unroll
      for (int r = 0; r < 4; ++r) qa[mi][r] += uv[r];
    }
    xpose(qa, g, bq_[nj][0], bq_[nj][1]);
  }

  // ---- accumulators ----
  f32x4 acc_o[2][4];                  // [nj][c-group]
  #pragma unroll
  for (int i = 0; i < 2; ++i)
    #pragma unroll
    for (int j = 0; j < 4; ++j) acc_o[i][j] = zero4();
  float dacc0 = 0.f, dacc1 = 0.f;

  #pragma unroll
  for (int vt = 0; vt < 4; ++vt) {
    // ---- S-GEMM (K32): ps[nj][mi] = S_T[v=16mi+4g+r][w=l15] ----
    f32x4 ps[2][4];
    #pragma unroll
    for (int mi = 0; mi < 4; ++mi) {
      short8 af0 = *(const short8*)swz(Xkv, vt * 64 + mi * 16 + l15, (8 * g) * 2);
      short8 af1 = *(const short8*)swz(Xkv, vt * 64 + mi * 16 + l15, (32 + 8 * g) * 2);
      #pragma unroll
      for (int nj = 0; nj < 2; ++nj) {
        ps[nj][mi] = zero4();
        ps[nj][mi] = __builtin_amdgcn_mfma_f32_16x16x32_bf16(af0, bq_[nj][0], ps[nj][mi], 0, 0, 0);
        ps[nj][mi] = __builtin_amdgcn_mfma_f32_16x16x32_bf16(af1, bq_[nj][1], ps[nj][mi], 0, 0, 0);
      }
    }
    // ---- exp (in place) + D accumulation ----
    #pragma unroll
    for (int nj = 0; nj < 2; ++nj) {
      float dl = 0.f;
      #pragma unroll
      for (int mi = 0; mi < 4; ++mi) {
        #pragma unroll
        for (int r = 0; r < 4; ++r)
          ps[nj][mi][r] = __expf(ps[nj][mi][r] * 0.015625f);
        dl += ps[nj][mi][0] + ps[nj][mi][1] + ps[nj][mi][2] + ps[nj][mi][3];
      }
      if (nj == 0) dacc0 += dl; else dacc1 += dl;
    }
    // ---- PV-GEMM (K16): P in C-layout is the A-fragment directly ----
    char* XnT = XnC + vt * 9216;
    #pragma unroll
    for (int mi = 0; mi < 4; ++mi) {
      short4v bv[4];
      #pragma unroll
      for (int nj2 = 0; nj2 < 4; ++nj2)
        bv[nj2] = *(const short4v*)(XnT + (nj2 * 16 + l15) * 144 + (mi * 16 + 4 * g) * 2);
      #pragma unroll
      for (int nj = 0; nj < 2; ++nj) {
        uint2v pw;
        pw[0] = pkw(ps[nj][mi][0], ps[nj][mi][1]);
        pw[1] = pkw(ps[nj][mi][2], ps[nj][mi][3]);
        short4v pa = __builtin_bit_cast(short4v, pw);
        #pragma unroll
        for (int nj2 = 0; nj2 < 4; ++nj2)
          acc_o[nj][nj2] = __builtin_amdgcn_mfma_f32_16x16x16bf16_1k(
              pa, bv[nj2], acc_o[nj][nj2], 0, 0, 0);
      }
    }
  } // vt

  // ---- D redistribute + epilogue (R10's Db-based version) ----
  float* outp = out + (at ? OUTHALF : 0) + (size_t)base_b * HW_ + rowOff;
  dacc0 += __shfl_xor(dacc0, 16); dacc0 += __shfl_xor(dacc0, 32);
  dacc1 += __shfl_xor(dacc1, 16); dacc1 += __shfl_xor(dacc1, 32);
  if (lane < 16) {
    Db[at * 256 + w0 + lane]      = __builtin_amdgcn_rcpf(dacc0);
    Db[at * 256 + w0 + 16 + lane] = __builtin_amdgcn_rcpf(dacc1);
  }
  #pragma unroll
  for (int nj = 0; nj < 2; ++nj) {
    f32x4 rd = *(const f32x4*)(Db + at * 256 + w0 + nj * 16 + 4 * g);
    #pragma unroll
    for (int nj2 = 0; nj2 < 4; ++nj2) {
      int c = nj2 * 16 + l15;
      f32x4 v;
      v[0] = acc_o[nj][nj2][0] * rd[0];
      v[1] = acc_o[nj][nj2][1] * rd[1];
      v[2] = acc_o[nj][nj2][2] * rd[2];
      v[3] = acc_o[nj][nj2][3] * rd[3];
      *(f32x4*)(outp + (size_t)c * HW_ + w0 + nj * 16 + 4 * g) = v;
    }
  }
}

extern "C" void kernel_launch(void* const* d_in, const int* in_sizes, int n_in,
                              void* d_out, int out_size, void* d_ws, size_t ws_size,
                              hipStream_t stream) {
  (void)in_sizes; (void)n_in; (void)out_size; (void)ws_size;
  const float* fl    = (const float*)d_in[0];
  const float* fr    = (const float*)d_in[1];
  const float* Wq    = (const float*)d_in[2];
  const float* bq    = (const float*)d_in[3];
  const float* gq    = (const float*)d_in[4];
  const float* betaq = (const float*)d_in[5];
  const float* mq    = (const float*)d_in[6];
  const float* vq    = (const float*)d_in[7];
  const float* Wk    = (const float*)d_in[8];
  const float* gk    = (const float*)d_in[10];
  const float* vk    = (const float*)d_in[13];
  short* Mbt = (short*)d_ws;
  float* u   = (float*)((char*)d_ws + 8192);
  float* out = (float*)d_out;

  hipFuncSetAttribute((const void*)pam_main,
                      hipFuncAttributeMaxDynamicSharedMemorySize, SMEM_BYTES);
  pam_setup<<<17, 256, 0, stream>>>(Wq, bq, gq, betaq, mq, vq, Wk, gk, vk, Mbt, u);
  pam_main<<<1024, 1024, SMEM_BYTES, stream>>>(fl, fr, Mbt, u, out);
}

// Round 15
// 114.300 us; speedup vs baseline: 2.1750x; 1.0120x over previous
//
#include <hip/hip_runtime.h>
#include <hip/hip_bf16.h>

// Problem constants (B=8, C=64, H=128, W=256)
#define HW_ 32768          // H*W
#define OUTHALF 16777216ULL
#define SMEM_BYTES 141312

typedef short short8  __attribute__((ext_vector_type(8)));
typedef short short4v __attribute__((ext_vector_type(4)));
typedef float f32x4   __attribute__((ext_vector_type(4)));
typedef unsigned int uint2v __attribute__((ext_vector_type(2)));
typedef unsigned int uint4v __attribute__((ext_vector_type(4)));

__device__ __forceinline__ unsigned short f2bf(float f) {
  unsigned u = __builtin_bit_cast(unsigned, f);
  u += 0x7fffu + ((u >> 16) & 1u);          // RNE; setup kernel only
  return (unsigned short)(u >> 16);
}
// native cast — compiler packs pairs into v_cvt_pk_bf16_f32 (R7-verified)
__device__ __forceinline__ short f2bfn(float f) {
  __hip_bfloat16 h = __float2bfloat16(f);
  return __builtin_bit_cast(short, h);
}
__device__ __forceinline__ unsigned pkw(float lo, float hi) {
  unsigned short a = (unsigned short)f2bfn(lo), b = (unsigned short)f2bfn(hi);
  return ((unsigned)b << 16) | (unsigned)a;
}
__device__ __forceinline__ char* swz(char* base, int row, int colByte) {
  // 128-byte rows; XOR bits 4-6 — proven for b128 reads (R1..R14)
  return base + row * 128 + (colByte ^ ((row & 7) << 4));
}
__device__ __forceinline__ f32x4 zero4() { f32x4 z = {0.f, 0.f, 0.f, 0.f}; return z; }

// In-register g-group transpose (R6-R14 verified). C-layout -> K32 A/B-fragment.
// Used once for the Q~ fragments.
__device__ __forceinline__ void xpose(const f32x4 (&p)[4], int g,
                                      short8& f0, short8& f1) {
  unsigned W00 = pkw(p[0][0], p[0][1]), W01 = pkw(p[0][2], p[0][3]);
  unsigned W10 = pkw(p[1][0], p[1][1]), W11 = pkw(p[1][2], p[1][3]);
  unsigned W20 = pkw(p[2][0], p[2][1]), W21 = pkw(p[2][2], p[2][3]);
  unsigned W30 = pkw(p[3][0], p[3][1]), W31 = pkw(p[3][2], p[3][3]);
  const bool h2 = (g & 2) != 0;
  unsigned SA0 = h2 ? W10 : W00, SA1 = h2 ? W11 : W01;
  unsigned SA2 = h2 ? W30 : W20, SA3 = h2 ? W31 : W21;
  unsigned SB0 = h2 ? W00 : W10, SB1 = h2 ? W01 : W11;
  unsigned SB2 = h2 ? W20 : W30, SB3 = h2 ? W21 : W31;
  unsigned ra0 = __shfl_xor((int)SA0, 16), ra1 = __shfl_xor((int)SA1, 16);
  unsigned ra2 = __shfl_xor((int)SA2, 16), ra3 = __shfl_xor((int)SA3, 16);
  unsigned rb0 = __shfl_xor((int)SB0, 32), rb1 = __shfl_xor((int)SB1, 32);
  unsigned rb2 = __shfl_xor((int)SB2, 32), rb3 = __shfl_xor((int)SB3, 32);
  unsigned rc0 = __shfl_xor((int)SB0, 48), rc1 = __shfl_xor((int)SB1, 48);
  unsigned rc2 = __shfl_xor((int)SB2, 48), rc3 = __shfl_xor((int)SB3, 48);
  unsigned a0 = g==0 ? SA0 : g==1 ? rc0 : g==2 ? rb0 : ra0;
  unsigned a1 = g==0 ? SA1 : g==1 ? rc1 : g==2 ? rb1 : ra1;
  unsigned a2 = g==0 ? SA2 : g==1 ? rc2 : g==2 ? rb2 : ra2;
  unsigned a3 = g==0 ? SA3 : g==1 ? rc3 : g==2 ? rb3 : ra3;
  unsigned b0 = g==3 ? SA0 : g==2 ? rc0 : g==1 ? rb0 : ra0;
  unsigned b1 = g==3 ? SA1 : g==2 ? rc1 : g==1 ? rb1 : ra1;
  unsigned b2 = g==3 ? SA2 : g==2 ? rc2 : g==1 ? rb2 : ra2;
  unsigned b3 = g==3 ? SA3 : g==2 ? rc3 : g==1 ? rb3 : ra3;
  uint4v u0 = {a0, a1, b0, b1};
  uint4v u1 = {a2, a3, b2, b3};
  f0 = __builtin_bit_cast(short8, u0);
  f1 = __builtin_bit_cast(short8, u1);
}

// ---------------- setup: Mbt[y][x] = sum_o Wq'[o][x] Wk'[o][y] (bf16), u[y]
__global__ void pam_setup(const float* __restrict__ Wq, const float* __restrict__ bq,
                          const float* __restrict__ gq, const float* __restrict__ betaq,
                          const float* __restrict__ mq, const float* __restrict__ vq,
                          const float* __restrict__ Wk, const float* __restrict__ gk,
                          const float* __restrict__ vk,
                          short* __restrict__ Mbt, float* __restrict__ u) {
  int blk = blockIdx.x, tid = threadIdx.x;
  if (blk < 16) {
    int entry = blk * 256 + tid;
    int y = entry >> 6, x = entry & 63;
    float acc = 0.f;
    for (int o = 0; o < 64; ++o) {
      float sq = gq[o] * rsqrtf(vq[o] + 1e-5f);
      float sk = gk[o] * rsqrtf(vk[o] + 1e-5f);
      acc += Wq[o * 64 + x] * sq * Wk[o * 64 + y] * sk;
    }
    Mbt[y * 64 + x] = (short)f2bf(acc);
  } else if (tid < 64) {
    int y = tid;
    float acc = 0.f;
    for (int o = 0; o < 64; ++o) {
      float sq = gq[o] * rsqrtf(vq[o] + 1e-5f);
      float sk = gk[o] * rsqrtf(vk[o] + 1e-5f);
      float bqq = bq[o] * sq + betaq[o] - mq[o] * sq;
      acc += bqq * Wk[o * 64 + y] * sk;
    }
    u[y] = acc;
  }
}

// ---------------- main: one block per (b,h); waves 0-7: at=0, waves 8-15: at=1.
// R14 structure; coalesced f32x4 slab staging + 1/64 folded into Q~.
__global__ __launch_bounds__(1024, 4) void pam_main(
    const float* __restrict__ fl, const float* __restrict__ fr,
    const short* __restrict__ Mbt, const float* __restrict__ uvec,
    float* __restrict__ out) {
  extern __shared__ __align__(16) char sm[];
  char* XLt = sm;                     // [256 pos][64 c] bf16 swizzled (128B rows)
  char* XRt = sm + 32768;
  char* Xn  = sm + 65536;             // [2 dir][4 vt][64 c][144B] padded rows
  float* Db = (float*)(sm + 139264);  // [2][256] 1/D

  const int tid  = threadIdx.x;
  const int lane = tid & 63;
  const int wave = tid >> 6;          // 0..15
  const int l15  = lane & 15;
  const int g    = lane >> 4;
  const int bb   = blockIdx.x >> 7;
  const int hh   = blockIdx.x & 127;
  const int rowOff = hh * 256;
  const int base_b = bb * 64;
  const int at   = wave >> 3;         // direction of this wave
  const int w0   = (wave & 7) * 32;   // this wave's 32 query rows

  // ---- stage XLt + XRt: f32x4 coalesced loads (16B/lane), 4x4 blocks ----
  #pragma unroll
  for (int it = 0; it < 2; ++it) {
    int unit = it * 1024 + tid;       // 0..2047
    int tensor = unit >> 10;
    int rem = unit & 1023;
    int cq = rem >> 6;                // channel quad 0..15
    int p  = (rem & 63) * 4;          // position base (4 consecutive)
    const float* s = (tensor ? fr : fl) + (size_t)(base_b + cq * 4) * HW_ + rowOff + p;
    f32x4 a0 = *(const f32x4*)(s);
    f32x4 a1 = *(const f32x4*)(s + HW_);
    f32x4 a2 = *(const f32x4*)(s + 2 * HW_);
    f32x4 a3 = *(const f32x4*)(s + 3 * HW_);
    char* dst = tensor ? XRt : XLt;
    #pragma unroll
    for (int j = 0; j < 4; ++j) {
      short4v pk;
      pk[0] = f2bfn(a0[j]); pk[1] = f2bfn(a1[j]);
      pk[2] = f2bfn(a2[j]); pk[3] = f2bfn(a3[j]);
      *(short4v*)swz(dst, p + j, cq * 8) = pk;
    }
  }
  // ---- stage V for both directions: Xn[dir][vt][c][144B] padded rows ----
  {
    const int dirT = tid >> 9;        // threads 0-511: dir0 (fr), 512-1023: dir1 (fl)
    const int vcc  = (tid >> 3) & 63; // channel
    const int vv8  = (tid & 7) * 8;   // 8 positions
    const float* srcv = dirT ? fl : fr;
    const float* vbase = srcv + (size_t)(base_b + vcc) * HW_ + rowOff + vv8;
    char* XnW = Xn + dirT * 36864 + vcc * 144 + vv8 * 2;
    #pragma unroll
    for (int vt = 0; vt < 4; ++vt) {
      f32x4 A0 = *(const f32x4*)(vbase + vt * 64);
      f32x4 A1 = *(const f32x4*)(vbase + vt * 64 + 4);
      short8 pk;
      pk[0] = f2bfn(A0[0]); pk[1] = f2bfn(A0[1]);
      pk[2] = f2bfn(A0[2]); pk[3] = f2bfn(A0[3]);
      pk[4] = f2bfn(A1[0]); pk[5] = f2bfn(A1[1]);
      pk[6] = f2bfn(A1[2]); pk[7] = f2bfn(A1[3]);
      *(short8*)(XnW + vt * 9216) = pk;
    }
  }
  __syncthreads();                    // the ONLY barrier

  char* Xq  = at ? XRt : XLt;         // query side
  char* Xkv = at ? XLt : XRt;         // key/value side (S-GEMM A operand)
  char* XnC = Xn + at * 36864;        // this direction's V

  // ---- Q^ = (M^T Xq + u)/64 (scale folded: 2^-6 exact in bf16) ----
  short8 bq_[2][2];                   // [nj][kk]
  #pragma unroll
  for (int nj = 0; nj < 2; ++nj) {
    short8 xb0 = *(const short8*)swz(Xq, w0 + nj * 16 + l15, (8 * g) * 2);
    short8 xb1 = *(const short8*)swz(Xq, w0 + nj * 16 + l15, (32 + 8 * g) * 2);
    f32x4 qa[4];
    #pragma unroll
    for (int mi = 0; mi < 4; ++mi) {
      qa[mi] = zero4();
      short8 am0 = *(const short8*)(Mbt + (mi * 16 + l15) * 64 + 8 * g);
      short8 am1 = *(const short8*)(Mbt + (mi * 16 + l15) * 64 + 32 + 8 * g);
      qa[mi] = __builtin_amdgcn_mfma_f32_16x16x32_bf16(am0, xb0, qa[mi], 0, 0, 0);
      qa[mi] = __builtin_amdgcn_mfma_f32_16x16x32_bf16(am1, xb1, qa[mi], 0, 0, 0);
      f32x4 uv = *(const f32x4*)(uvec + mi * 16 + 4 * g);
      #pragma unroll
      for (int r = 0; r < 4; ++r) qa[mi][r] = (qa[mi][r] + uv[r]) * 0.015625f;
    }
    xpose(qa, g, bq_[nj][0], bq_[nj][1]);
  }

  // ---- accumulators ----
  f32x4 acc_o[2][4];                  // [nj][c-group]
  #pragma unroll
  for (int i = 0; i < 2; ++i)
    #pragma unroll
    for (int j = 0; j < 4; ++j) acc_o[i][j] = zero4();
  float dacc0 = 0.f, dacc1 = 0.f;

  #pragma unroll
  for (int vt = 0; vt < 4; ++vt) {
    // ---- S-GEMM (K32): ps[nj][mi] = S_T[v=16mi+4g+r][w=l15] (pre-scaled) ----
    f32x4 ps[2][4];
    #pragma unroll
    for (int mi = 0; mi < 4; ++mi) {
      short8 af0 = *(const short8*)swz(Xkv, vt * 64 + mi * 16 + l15, (8 * g) * 2);
      short8 af1 = *(const short8*)swz(Xkv, vt * 64 + mi * 16 + l15, (32 + 8 * g) * 2);
      #pragma unroll
      for (int nj = 0; nj < 2; ++nj) {
        ps[nj][mi] = zero4();
        ps[nj][mi] = __builtin_amdgcn_mfma_f32_16x16x32_bf16(af0, bq_[nj][0], ps[nj][mi], 0, 0, 0);
        ps[nj][mi] = __builtin_amdgcn_mfma_f32_16x16x32_bf16(af1, bq_[nj][1], ps[nj][mi], 0, 0, 0);
      }
    }
    // ---- exp (in place, no mul) + D accumulation ----
    #pragma unroll
    for (int nj = 0; nj < 2; ++nj) {
      float dl = 0.f;
      #pragma unroll
      for (int mi = 0; mi < 4; ++mi) {
        #pragma unroll
        for (int r = 0; r < 4; ++r)
          ps[nj][mi][r] = __expf(ps[nj][mi][r]);
        dl += ps[nj][mi][0] + ps[nj][mi][1] + ps[nj][mi][2] + ps[nj][mi][3];
      }
      if (nj == 0) dacc0 += dl; else dacc1 += dl;
    }
    // ---- PV-GEMM (K16): P in C-layout is the A-fragment directly ----
    char* XnT = XnC + vt * 9216;
    #pragma unroll
    for (int mi = 0; mi < 4; ++mi) {
      short4v bv[4];
      #pragma unroll
      for (int nj2 = 0; nj2 < 4; ++nj2)
        bv[nj2] = *(const short4v*)(XnT + (nj2 * 16 + l15) * 144 + (mi * 16 + 4 * g) * 2);
      #pragma unroll
      for (int nj = 0; nj < 2; ++nj) {
        uint2v pw;
        pw[0] = pkw(ps[nj][mi][0], ps[nj][mi][1]);
        pw[1] = pkw(ps[nj][mi][2], ps[nj][mi][3]);
        short4v pa = __builtin_bit_cast(short4v, pw);
        #pragma unroll
        for (int nj2 = 0; nj2 < 4; ++nj2)
          acc_o[nj][nj2] = __builtin_amdgcn_mfma_f32_16x16x16bf16_1k(
              pa, bv[nj2], acc_o[nj][nj2], 0, 0, 0);
      }
    }
  } // vt

  // ---- D redistribute + epilogue (R10/R14 Db-based version) ----
  float* outp = out + (at ? OUTHALF : 0) + (size_t)base_b * HW_ + rowOff;
  dacc0 += __shfl_xor(dacc0, 16); dacc0 += __shfl_xor(dacc0, 32);
  dacc1 += __shfl_xor(dacc1, 16); dacc1 += __shfl_xor(dacc1, 32);
  if (lane < 16) {
    Db[at * 256 + w0 + lane]      = __builtin_amdgcn_rcpf(dacc0);
    Db[at * 256 + w0 + 16 + lane] = __builtin_amdgcn_rcpf(dacc1);
  }
  #pragma unroll
  for (int nj = 0; nj < 2; ++nj) {
    f32x4 rd = *(const f32x4*)(Db + at * 256 + w0 + nj * 16 + 4 * g);
    #pragma unroll
    for (int nj2 = 0; nj2 < 4; ++nj2) {
      int c = nj2 * 16 + l15;
      f32x4 v;
      v[0] = acc_o[nj][nj2][0] * rd[0];
      v[1] = acc_o[nj][nj2][1] * rd[1];
      v[2] = acc_o[nj][nj2][2] * rd[2];
      v[3] = acc_o[nj][nj2][3] * rd[3];
      *(f32x4*)(outp + (size_t)c * HW_ + w0 + nj * 16 + 4 * g) = v;
    }
  }
}

extern "C" void kernel_launch(void* const* d_in, const int* in_sizes, int n_in,
                              void* d_out, int out_size, void* d_ws, size_t ws_size,
                              hipStream_t stream) {
  (void)in_sizes; (void)n_in; (void)out_size; (void)ws_size;
  const float* fl    = (const float*)d_in[0];
  const float* fr    = (const float*)d_in[1];
  const float* Wq    = (const float*)d_in[2];
  const float* bq    = (const float*)d_in[3];
  const float* gq    = (const float*)d_in[4];
  const float* betaq = (const float*)d_in[5];
  const float* mq    = (const float*)d_in[6];
  const float* vq    = (const float*)d_in[7];
  const float* Wk    = (const float*)d_in[8];
  const float* gk    = (const float*)d_in[10];
  const float* vk    = (const float*)d_in[13];
  short* Mbt = (short*)d_ws;
  float* u   = (float*)((char*)d_ws + 8192);
  float* out = (float*)d_out;

  hipFuncSetAttribute((const void*)pam_main,
                      hipFuncAttributeMaxDynamicSharedMemorySize, SMEM_BYTES);
  pam_setup<<<17, 256, 0, stream>>>(Wq, bq, gq, betaq, mq, vq, Wk, gk, vk, Mbt, u);
  pam_main<<<1024, 1024, SMEM_BYTES, stream>>>(fl, fr, Mbt, u, out);
}

// Round 17
// 111.600 us; speedup vs baseline: 2.2276x; 1.0242x over previous
//
#include <hip/hip_runtime.h>
#include <hip/hip_bf16.h>

// Problem constants (B=8, C=64, H=128, W=256)
#define HW_ 32768          // H*W
#define OUTHALF 16777216ULL
#define SMEM_BYTES 141312

typedef short short8  __attribute__((ext_vector_type(8)));
typedef short short4v __attribute__((ext_vector_type(4)));
typedef float f32x4   __attribute__((ext_vector_type(4)));
typedef unsigned int uint2v __attribute__((ext_vector_type(2)));
typedef unsigned int uint4v __attribute__((ext_vector_type(4)));

__device__ __forceinline__ unsigned short f2bf(float f) {
  unsigned u = __builtin_bit_cast(unsigned, f);
  u += 0x7fffu + ((u >> 16) & 1u);          // RNE; setup kernel only
  return (unsigned short)(u >> 16);
}
// native cast — compiler packs pairs into v_cvt_pk_bf16_f32 (R7-verified)
__device__ __forceinline__ short f2bfn(float f) {
  __hip_bfloat16 h = __float2bfloat16(f);
  return __builtin_bit_cast(short, h);
}
__device__ __forceinline__ unsigned pkw(float lo, float hi) {
  unsigned short a = (unsigned short)f2bfn(lo), b = (unsigned short)f2bfn(hi);
  return ((unsigned)b << 16) | (unsigned)a;
}
__device__ __forceinline__ char* swz(char* base, int row, int colByte) {
  // 128-byte rows; XOR bits 4-6 — proven for b128 reads (R1..R15)
  return base + row * 128 + (colByte ^ ((row & 7) << 4));
}
__device__ __forceinline__ f32x4 zero4() { f32x4 z = {0.f, 0.f, 0.f, 0.f}; return z; }

// In-register g-group transpose (R6-R15 verified). C-layout -> K32 A/B-fragment.
// Used once for the Q~ fragments.
__device__ __forceinline__ void xpose(const f32x4 (&p)[4], int g,
                                      short8& f0, short8& f1) {
  unsigned W00 = pkw(p[0][0], p[0][1]), W01 = pkw(p[0][2], p[0][3]);
  unsigned W10 = pkw(p[1][0], p[1][1]), W11 = pkw(p[1][2], p[1][3]);
  unsigned W20 = pkw(p[2][0], p[2][1]), W21 = pkw(p[2][2], p[2][3]);
  unsigned W30 = pkw(p[3][0], p[3][1]), W31 = pkw(p[3][2], p[3][3]);
  const bool h2 = (g & 2) != 0;
  unsigned SA0 = h2 ? W10 : W00, SA1 = h2 ? W11 : W01;
  unsigned SA2 = h2 ? W30 : W20, SA3 = h2 ? W31 : W21;
  unsigned SB0 = h2 ? W00 : W10, SB1 = h2 ? W01 : W11;
  unsigned SB2 = h2 ? W20 : W30, SB3 = h2 ? W21 : W31;
  unsigned ra0 = __shfl_xor((int)SA0, 16), ra1 = __shfl_xor((int)SA1, 16);
  unsigned ra2 = __shfl_xor((int)SA2, 16), ra3 = __shfl_xor((int)SA3, 16);
  unsigned rb0 = __shfl_xor((int)SB0, 32), rb1 = __shfl_xor((int)SB1, 32);
  unsigned rb2 = __shfl_xor((int)SB2, 32), rb3 = __shfl_xor((int)SB3, 32);
  unsigned rc0 = __shfl_xor((int)SB0, 48), rc1 = __shfl_xor((int)SB1, 48);
  unsigned rc2 = __shfl_xor((int)SB2, 48), rc3 = __shfl_xor((int)SB3, 48);
  unsigned a0 = g==0 ? SA0 : g==1 ? rc0 : g==2 ? rb0 : ra0;
  unsigned a1 = g==0 ? SA1 : g==1 ? rc1 : g==2 ? rb1 : ra1;
  unsigned a2 = g==0 ? SA2 : g==1 ? rc2 : g==2 ? rb2 : ra2;
  unsigned a3 = g==0 ? SA3 : g==1 ? rc3 : g==2 ? rb3 : ra3;
  unsigned b0 = g==3 ? SA0 : g==2 ? rc0 : g==1 ? rb0 : ra0;
  unsigned b1 = g==3 ? SA1 : g==2 ? rc1 : g==1 ? rb1 : ra1;
  unsigned b2 = g==3 ? SA2 : g==2 ? rc2 : g==1 ? rb2 : ra2;
  unsigned b3 = g==3 ? SA3 : g==2 ? rc3 : g==1 ? rb3 : ra3;
  uint4v u0 = {a0, a1, b0, b1};
  uint4v u1 = {a2, a3, b2, b3};
  f0 = __builtin_bit_cast(short8, u0);
  f1 = __builtin_bit_cast(short8, u1);
}

// ---------------- setup: Mbt[y][x] = sum_o Wq'[o][x] Wk'[o][y] (bf16), u[y]
__global__ void pam_setup(const float* __restrict__ Wq, const float* __restrict__ bq,
                          const float* __restrict__ gq, const float* __restrict__ betaq,
                          const float* __restrict__ mq, const float* __restrict__ vq,
                          const float* __restrict__ Wk, const float* __restrict__ gk,
                          const float* __restrict__ vk,
                          short* __restrict__ Mbt, float* __restrict__ u) {
  int blk = blockIdx.x, tid = threadIdx.x;
  if (blk < 16) {
    int entry = blk * 256 + tid;
    int y = entry >> 6, x = entry & 63;
    float acc = 0.f;
    for (int o = 0; o < 64; ++o) {
      float sq = gq[o] * rsqrtf(vq[o] + 1e-5f);
      float sk = gk[o] * rsqrtf(vk[o] + 1e-5f);
      acc += Wq[o * 64 + x] * sq * Wk[o * 64 + y] * sk;
    }
    Mbt[y * 64 + x] = (short)f2bf(acc);
  } else if (tid < 64) {
    int y = tid;
    float acc = 0.f;
    for (int o = 0; o < 64; ++o) {
      float sq = gq[o] * rsqrtf(vq[o] + 1e-5f);
      float sk = gk[o] * rsqrtf(vk[o] + 1e-5f);
      float bqq = bq[o] * sq + betaq[o] - mq[o] * sq;
      acc += bqq * Wk[o * 64 + y] * sk;
    }
    u[y] = acc;
  }
}

// ---------------- main: one block per (b,h); waves 0-7: at=0, waves 8-15: at=1.
// R15 structure; bank-spread staging writes + log2e fold (exp2 path).
__global__ __launch_bounds__(1024, 4) void pam_main(
    const float* __restrict__ fl, const float* __restrict__ fr,
    const short* __restrict__ Mbt, const float* __restrict__ uvec,
    float* __restrict__ out) {
  extern __shared__ __align__(16) char sm[];
  char* XLt = sm;                     // [256 pos][64 c] bf16 swizzled (128B rows)
  char* XRt = sm + 32768;
  char* Xn  = sm + 65536;             // [2 dir][4 vt][64 c][144B] padded rows
  float* Db = (float*)(sm + 139264);  // [2][256] 1/D

  const int tid  = threadIdx.x;
  const int lane = tid & 63;
  const int wave = tid >> 6;          // 0..15
  const int l15  = lane & 15;
  const int g    = lane >> 4;
  const int bb   = blockIdx.x >> 7;
  const int hh   = blockIdx.x & 127;
  const int rowOff = hh * 256;
  const int base_b = bb * 64;
  const int at   = wave >> 3;         // direction of this wave
  const int w0   = (wave & 7) * 32;   // this wave's 32 query rows

  // ---- stage XLt + XRt: lanes spread across 16 cq x 4 row-blocks so each
  // LDS write instruction covers many banks (was: 64 rows x 1 cq = 8 banks) ----
  #pragma unroll
  for (int it = 0; it < 2; ++it) {
    int u10 = (it * 1024 + tid) & 1023;
    int tensor = it;                  // it=0: fl, it=1: fr (tid spans 1024)
    int cq = u10 & 15;                // channel quad 0..15
    int p  = ((u10 >> 4) & 63) * 4;   // position base (4 consecutive)
    const float* s = (tensor ? fr : fl) + (size_t)(base_b + cq * 4) * HW_ + rowOff + p;
    f32x4 a0 = *(const f32x4*)(s);
    f32x4 a1 = *(const f32x4*)(s + HW_);
    f32x4 a2 = *(const f32x4*)(s + 2 * HW_);
    f32x4 a3 = *(const f32x4*)(s + 3 * HW_);
    char* dst = tensor ? XRt : XLt;
    #pragma unroll
    for (int j = 0; j < 4; ++j) {
      short4v pk;
      pk[0] = f2bfn(a0[j]); pk[1] = f2bfn(a1[j]);
      pk[2] = f2bfn(a2[j]); pk[3] = f2bfn(a3[j]);
      *(short4v*)swz(dst, p + j, cq * 8) = pk;
    }
  }
  // ---- stage V for both directions: Xn[dir][vt][c][144B] padded rows ----
  {
    const int dirT = tid >> 9;        // threads 0-511: dir0 (fr), 512-1023: dir1 (fl)
    const int vcc  = (tid >> 3) & 63; // channel
    const int vv8  = (tid & 7) * 8;   // 8 positions
    const float* srcv = dirT ? fl : fr;
    const float* vbase = srcv + (size_t)(base_b + vcc) * HW_ + rowOff + vv8;
    char* XnW = Xn + dirT * 36864 + vcc * 144 + vv8 * 2;
    #pragma unroll
    for (int vt = 0; vt < 4; ++vt) {
      f32x4 A0 = *(const f32x4*)(vbase + vt * 64);
      f32x4 A1 = *(const f32x4*)(vbase + vt * 64 + 4);
      short8 pk;
      pk[0] = f2bfn(A0[0]); pk[1] = f2bfn(A0[1]);
      pk[2] = f2bfn(A0[2]); pk[3] = f2bfn(A0[3]);
      pk[4] = f2bfn(A1[0]); pk[5] = f2bfn(A1[1]);
      pk[6] = f2bfn(A1[2]); pk[7] = f2bfn(A1[3]);
      *(short8*)(XnW + vt * 9216) = pk;
    }
  }
  __syncthreads();                    // the ONLY barrier

  char* Xq  = at ? XRt : XLt;         // query side
  char* Xkv = at ? XLt : XRt;         // key/value side (S-GEMM A operand)
  char* XnC = Xn + at * 36864;        // this direction's V

  // ---- Q^ = (M^T Xq + u)*log2e/64 (exp2 fold) ----
  short8 bq_[2][2];                   // [nj][kk]
  #pragma unroll
  for (int nj = 0; nj < 2; ++nj) {
    short8 xb0 = *(const short8*)swz(Xq, w0 + nj * 16 + l15, (8 * g) * 2);
    short8 xb1 = *(const short8*)swz(Xq, w0 + nj * 16 + l15, (32 + 8 * g) * 2);
    f32x4 qa[4];
    #pragma unroll
    for (int mi = 0; mi < 4; ++mi) {
      qa[mi] = zero4();
      short8 am0 = *(const short8*)(Mbt + (mi * 16 + l15) * 64 + 8 * g);
      short8 am1 = *(const short8*)(Mbt + (mi * 16 + l15) * 64 + 32 + 8 * g);
      qa[mi] = __builtin_amdgcn_mfma_f32_16x16x32_bf16(am0, xb0, qa[mi], 0, 0, 0);
      qa[mi] = __builtin_amdgcn_mfma_f32_16x16x32_bf16(am1, xb1, qa[mi], 0, 0, 0);
      f32x4 uv = *(const f32x4*)(uvec + mi * 16 + 4 * g);
      #pragma unroll
      for (int r = 0; r < 4; ++r)
        qa[mi][r] = (qa[mi][r] + uv[r]) * (0.015625f * 1.44269504089f);
    }
    xpose(qa, g, bq_[nj][0], bq_[nj][1]);
  }

  // ---- accumulators ----
  f32x4 acc_o[2][4];                  // [nj][c-group]
  #pragma unroll
  for (int i = 0; i < 2; ++i)
    #pragma unroll
    for (int j = 0; j < 4; ++j) acc_o[i][j] = zero4();
  float dacc0 = 0.f, dacc1 = 0.f;

  #pragma unroll
  for (int vt = 0; vt < 4; ++vt) {
    // ---- S-GEMM (K32): ps[nj][mi] = S_T[v=16mi+4g+r][w=l15] (log2-domain) ----
    f32x4 ps[2][4];
    #pragma unroll
    for (int mi = 0; mi < 4; ++mi) {
      short8 af0 = *(const short8*)swz(Xkv, vt * 64 + mi * 16 + l15, (8 * g) * 2);
      short8 af1 = *(const short8*)swz(Xkv, vt * 64 + mi * 16 + l15, (32 + 8 * g) * 2);
      #pragma unroll
      for (int nj = 0; nj < 2; ++nj) {
        ps[nj][mi] = zero4();
        ps[nj][mi] = __builtin_amdgcn_mfma_f32_16x16x32_bf16(af0, bq_[nj][0], ps[nj][mi], 0, 0, 0);
        ps[nj][mi] = __builtin_amdgcn_mfma_f32_16x16x32_bf16(af1, bq_[nj][1], ps[nj][mi], 0, 0, 0);
      }
    }
    // ---- exp2 (native v_exp_f32, no mul) + D accumulation ----
    #pragma unroll
    for (int nj = 0; nj < 2; ++nj) {
      float dl = 0.f;
      #pragma unroll
      for (int mi = 0; mi < 4; ++mi) {
        #pragma unroll
        for (int r = 0; r < 4; ++r)
          ps[nj][mi][r] = __builtin_amdgcn_exp2f(ps[nj][mi][r]);
        dl += ps[nj][mi][0] + ps[nj][mi][1] + ps[nj][mi][2] + ps[nj][mi][3];
      }
      if (nj == 0) dacc0 += dl; else dacc1 += dl;
    }
    // ---- PV-GEMM (K16): P in C-layout is the A-fragment directly ----
    char* XnT = XnC + vt * 9216;
    #pragma unroll
    for (int mi = 0; mi < 4; ++mi) {
      short4v bv[4];
      #pragma unroll
      for (int nj2 = 0; nj2 < 4; ++nj2)
        bv[nj2] = *(const short4v*)(XnT + (nj2 * 16 + l15) * 144 + (mi * 16 + 4 * g) * 2);
      #pragma unroll
      for (int nj = 0; nj < 2; ++nj) {
        uint2v pw;
        pw[0] = pkw(ps[nj][mi][0], ps[nj][mi][1]);
        pw[1] = pkw(ps[nj][mi][2], ps[nj][mi][3]);
        short4v pa = __builtin_bit_cast(short4v, pw);
        #pragma unroll
        for (int nj2 = 0; nj2 < 4; ++nj2)
          acc_o[nj][nj2] = __builtin_amdgcn_mfma_f32_16x16x16bf16_1k(
              pa, bv[nj2], acc_o[nj][nj2], 0, 0, 0);
      }
    }
  } // vt

  // ---- D redistribute + epilogue (R10/R14/R15 Db-based version) ----
  float* outp = out + (at ? OUTHALF : 0) + (size_t)base_b * HW_ + rowOff;
  dacc0 += __shfl_xor(dacc0, 16); dacc0 += __shfl_xor(dacc0, 32);
  dacc1 += __shfl_xor(dacc1, 16); dacc1 += __shfl_xor(dacc1, 32);
  if (lane < 16) {
    Db[at * 256 + w0 + lane]      = __builtin_amdgcn_rcpf(dacc0);
    Db[at * 256 + w0 + 16 + lane] = __builtin_amdgcn_rcpf(dacc1);
  }
  #pragma unroll
  for (int nj = 0; nj < 2; ++nj) {
    f32x4 rd = *(const f32x4*)(Db + at * 256 + w0 + nj * 16 + 4 * g);
    #pragma unroll
    for (int nj2 = 0; nj2 < 4; ++nj2) {
      int c = nj2 * 16 + l15;
      f32x4 v;
      v[0] = acc_o[nj][nj2][0] * rd[0];
      v[1] = acc_o[nj][nj2][1] * rd[1];
      v[2] = acc_o[nj][nj2][2] * rd[2];
      v[3] = acc_o[nj][nj2][3] * rd[3];
      *(f32x4*)(outp + (size_t)c * HW_ + w0 + nj * 16 + 4 * g) = v;
    }
  }
}

extern "C" void kernel_launch(void* const* d_in, const int* in_sizes, int n_in,
                              void* d_out, int out_size, void* d_ws, size_t ws_size,
                              hipStream_t stream) {
  (void)in_sizes; (void)n_in; (void)out_size; (void)ws_size;
  const float* fl    = (const float*)d_in[0];
  const float* fr    = (const float*)d_in[1];
  const float* Wq    = (const float*)d_in[2];
  const float* bq    = (const float*)d_in[3];
  const float* gq    = (const float*)d_in[4];
  const float* betaq = (const float*)d_in[5];
  const float* mq    = (const float*)d_in[6];
  const float* vq    = (const float*)d_in[7];
  const float* Wk    = (const float*)d_in[8];
  const float* gk    = (const float*)d_in[10];
  const float* vk    = (const float*)d_in[13];
  short* Mbt = (short*)d_ws;
  float* u   = (float*)((char*)d_ws + 8192);
  float* out = (float*)d_out;

  hipFuncSetAttribute((const void*)pam_main,
                      hipFuncAttributeMaxDynamicSharedMemorySize, SMEM_BYTES);
  pam_setup<<<17, 256, 0, stream>>>(Wq, bq, gq, betaq, mq, vq, Wk, gk, vk, Mbt, u);
  pam_main<<<1024, 1024, SMEM_BYTES, stream>>>(fl, fr, Mbt, u, out);
}